// Round 1
// baseline (174.445 us; speedup 1.0000x reference)
//
#include <hip/hip_runtime.h>
#include <stdint.h>

// Problem constants (match reference)
#define BB      4
#define NPTS    120000
#define GX      432
#define GY      496
#define GG      (GX*GY)        // 214272 cells
#define MAXVOX  40000
#define MAXP    32
#define NB      ((NPTS + 255) / 256)   // 469 blocks per batch

// Output layout in d_out (float32):
//   pillars : [0, 20480000)            (B*MAXVOX*MAXP*4)
//   coors   : [20480000, 21120000)     (B*MAXVOX*4)  values: b,cx,cy,cz or -1s
//   npts    : [21120000, 21280000)     (B*MAXVOX)
#define OFF_COOR 20480000
#define OFF_NPTS 21120000

// K1: per point — voxel flat id, first-point atomicMin, count atomicAdd
__global__ __launch_bounds__(256) void k1_flat(const float* __restrict__ pts,
        int* __restrict__ flat_id, int* __restrict__ dfirst, int* __restrict__ dcnt)
{
    int p = blockIdx.x * 256 + threadIdx.x;
    int b = blockIdx.y;
    if (p >= NPTS) return;
    const float4 pt = ((const float4*)pts)[(size_t)b * NPTS + p];
    float x = pt.x, y = pt.y, z = pt.z;
    bool inb = (x >= 0.0f) && (x < 69.12f) &&
               (y >= -39.68f) && (y < 39.68f) &&
               (z >= -3.0f) && (z < 1.0f);
    int flat = -1;
    if (inb) {
        // exact same fp ops as reference: (v - lo) / vs, floor, clip
        int cx = (int)floorf((x - 0.0f) / 0.16f);
        int cy = (int)floorf((y - (-39.68f)) / 0.16f);
        cx = min(max(cx, 0), GX - 1);
        cy = min(max(cy, 0), GY - 1);
        flat = cx * GY + cy;          // cz always clips to 0 (grid_z = 1)
        atomicMin(&dfirst[b * GG + flat], p);
        atomicAdd(&dcnt[b * GG + flat], 1);
    }
    flat_id[b * NPTS + p] = flat;
}

// K2: per-block sum of "is first point of its voxel" flags
__global__ __launch_bounds__(256) void k2_blocksum(const int* __restrict__ flat_id,
        const int* __restrict__ dfirst, int* __restrict__ partials)
{
    int p = blockIdx.x * 256 + threadIdx.x;
    int b = blockIdx.y;
    int flag = 0;
    if (p < NPTS) {
        int f = flat_id[b * NPTS + p];
        if (f >= 0 && dfirst[b * GG + f] == p) flag = 1;
    }
    unsigned long long m = __ballot(flag);
    __shared__ int ws[4];
    int lane = threadIdx.x & 63, wv = threadIdx.x >> 6;
    if (lane == 0) ws[wv] = __popcll(m);
    __syncthreads();
    if (threadIdx.x == 0)
        partials[b * NB + blockIdx.x] = ws[0] + ws[1] + ws[2] + ws[3];
}

// K3: exclusive scan of NB=469 partials per batch (one block per batch)
__global__ __launch_bounds__(512) void k3_scan(int* __restrict__ partials)
{
    __shared__ int s[512];
    int b = blockIdx.x;
    int t = threadIdx.x;
    int v = (t < NB) ? partials[b * NB + t] : 0;
    s[t] = v;
    __syncthreads();
    for (int off = 1; off < 512; off <<= 1) {
        int add = (t >= off) ? s[t - off] : 0;
        __syncthreads();
        s[t] += add;
        __syncthreads();
    }
    if (t < NB) partials[b * NB + t] = s[t] - v;   // exclusive
}

// K4: first points compute their voxel's slot (first-occurrence rank),
//     record slot per voxel + voxel per slot
__global__ __launch_bounds__(256) void k4_slots(const int* __restrict__ flat_id,
        const int* __restrict__ dfirst, const int* __restrict__ partials,
        int* __restrict__ dslot, int* __restrict__ slot_voxel)
{
    int p = blockIdx.x * 256 + threadIdx.x;
    int b = blockIdx.y;
    int flag = 0; int f = -1;
    if (p < NPTS) {
        f = flat_id[b * NPTS + p];
        if (!(f >= 0 && dfirst[b * GG + f] == p)) f = -1;
        else flag = 1;
    }
    unsigned long long mask = __ballot(flag);
    int lane = threadIdx.x & 63, wv = threadIdx.x >> 6;
    __shared__ int ws[4];
    if (lane == 0) ws[wv] = __popcll(mask);
    __syncthreads();
    int wo = 0;
    for (int i = 0; i < wv; ++i) wo += ws[i];
    if (flag) {
        int local = wo + __popcll(mask & ((1ull << lane) - 1ull));
        int slot = partials[b * NB + blockIdx.x] + local;
        dslot[b * GG + f] = slot;                       // always (even >= MAXVOX)
        if (slot < MAXVOX) slot_voxel[b * MAXVOX + slot] = f;
    }
}

// K5: gather point indices per kept slot (arbitrary order; sorted in K6)
__global__ __launch_bounds__(256) void k5_fill(const int* __restrict__ flat_id,
        const int* __restrict__ dslot, int* __restrict__ slot_cnt,
        int* __restrict__ lists)
{
    int p = blockIdx.x * 256 + threadIdx.x;
    int b = blockIdx.y;
    if (p >= NPTS) return;
    int f = flat_id[b * NPTS + p];
    if (f < 0) return;
    int slot = dslot[b * GG + f];
    if (slot >= MAXVOX) return;
    int pos = atomicAdd(&slot_cnt[b * MAXVOX + slot], 1);
    if (pos < MAXP) lists[(size_t)(b * MAXVOX + slot) * MAXP + pos] = p;
}

// K6: per slot — sort <=32 indices (restores point order), emit outputs
__global__ __launch_bounds__(256) void k6_out(const float* __restrict__ pts,
        const int* __restrict__ slot_voxel, const int* __restrict__ dcnt,
        const int* __restrict__ lists, float* __restrict__ out)
{
    int t = blockIdx.x * 256 + threadIdx.x;
    if (t >= BB * MAXVOX) return;
    int b = t / MAXVOX;
    float* coor = out + (size_t)OFF_COOR + (size_t)t * 4;
    float* nrow = out + (size_t)OFF_NPTS + t;
    int v = slot_voxel[t];
    if (v < 0) {
        coor[0] = -1.f; coor[1] = -1.f; coor[2] = -1.f; coor[3] = -1.f;
        nrow[0] = 0.f;
        return;
    }
    int cnt = dcnt[b * GG + v];
    int m = min(cnt, MAXP);
    int idxs[MAXP];
    const int* lp = lists + (size_t)t * MAXP;
    for (int r = 0; r < m; ++r) idxs[r] = lp[r];
    for (int i = 1; i < m; ++i) {          // insertion sort, m typically 1-3
        int key = idxs[i]; int j = i - 1;
        while (j >= 0 && idxs[j] > key) { idxs[j + 1] = idxs[j]; --j; }
        idxs[j + 1] = key;
    }
    const float4* pp = (const float4*)pts;
    float4* prow = (float4*)out + (size_t)t * MAXP;
    for (int r = 0; r < m; ++r)
        prow[r] = pp[(size_t)b * NPTS + idxs[r]];
    coor[0] = (float)b;
    coor[1] = (float)(v / GY);
    coor[2] = (float)(v % GY);
    coor[3] = 0.f;
    nrow[0] = (float)m;
}

extern "C" void kernel_launch(void* const* d_in, const int* in_sizes, int n_in,
                              void* d_out, int out_size, void* d_ws, size_t ws_size,
                              hipStream_t stream) {
    const float* pts = (const float*)d_in[0];
    float* out = (float*)d_out;

    // workspace carve-up (256B aligned), total ~33.6 MB
    auto align256 = [](size_t x) { return (x + 255) & ~(size_t)255; };
    char* w = (char*)d_ws;
    int* flat_id    = (int*)w;  w += align256((size_t)BB * NPTS * 4);
    int* dfirst     = (int*)w;  w += align256((size_t)BB * GG * 4);
    int* dcnt       = (int*)w;  w += align256((size_t)BB * GG * 4);
    int* dslot      = (int*)w;  w += align256((size_t)BB * GG * 4);
    int* partials   = (int*)w;  w += align256((size_t)BB * NB * 4);
    int* slot_voxel = (int*)w;  w += align256((size_t)BB * MAXVOX * 4);
    int* slot_cnt   = (int*)w;  w += align256((size_t)BB * MAXVOX * 4);
    int* lists      = (int*)w;  w += align256((size_t)BB * MAXVOX * MAXP * 4);

    // init (d_out / d_ws are poisoned 0xAA before every call)
    hipMemsetAsync(out, 0, (size_t)OFF_COOR * 4, stream);          // pillars = 0
    hipMemsetAsync(dfirst, 0x7F, (size_t)BB * GG * 4, stream);     // first = big
    hipMemsetAsync(dcnt, 0, (size_t)BB * GG * 4, stream);
    hipMemsetAsync(slot_voxel, 0xFF, (size_t)BB * MAXVOX * 4, stream);  // -1
    hipMemsetAsync(slot_cnt, 0, (size_t)BB * MAXVOX * 4, stream);

    dim3 gp(NB, BB);
    k1_flat   <<<gp, 256, 0, stream>>>(pts, flat_id, dfirst, dcnt);
    k2_blocksum<<<gp, 256, 0, stream>>>(flat_id, dfirst, partials);
    k3_scan   <<<BB, 512, 0, stream>>>(partials);
    k4_slots  <<<gp, 256, 0, stream>>>(flat_id, dfirst, partials, dslot, slot_voxel);
    k5_fill   <<<gp, 256, 0, stream>>>(flat_id, dslot, slot_cnt, lists);
    k6_out    <<<(BB * MAXVOX + 255) / 256, 256, 0, stream>>>(pts, slot_voxel, dcnt, lists, out);
}